// Round 1
// baseline (480.572 us; speedup 1.0000x reference)
//
#include <hip/hip_runtime.h>
#include <math.h>

typedef _Float16 half_t;
typedef __attribute__((ext_vector_type(8))) _Float16 half8;
typedef __attribute__((ext_vector_type(16))) float floatx16;

__device__ __forceinline__ float gelu_exact(float v) {
    return 0.5f * v * (1.0f + erff(v * 0.7071067811865476f));
}

__device__ __forceinline__ floatx16 zero16() {
    floatx16 z;
#pragma unroll
    for (int i = 0; i < 16; ++i) z[i] = 0.f;
    return z;
}

// LDS byte-offset swizzle: kills the 16-way conflict on 512B-strided staging
// writes while keeping the (already conflict-free) fragment reads conflict-free.
// Applied identically on write and read -> correctness by construction.
__device__ __forceinline__ int swz(int b) { return b ^ (((b >> 9) & 7) << 4); }

#define MFMA16(a, b, c) __builtin_amdgcn_mfma_f32_32x32x16_f16((a), (b), (c), 0, 0, 0)

// ---------------- prep ---------------- (unchanged; layout validated in prior rounds)
__global__ __launch_bounds__(256) void prep(const float* __restrict__ W0,
                                            const float* __restrict__ A0,
                                            const float* __restrict__ W1,
                                            const float* __restrict__ A1,
                                            half_t* __restrict__ Wsw0, half_t* __restrict__ Wsw1,
                                            half_t* __restrict__ Zah0, half_t* __restrict__ Zal0,
                                            half_t* __restrict__ Zah1, half_t* __restrict__ Zal1) {
    __shared__ float tile[32][257];
    const int t  = threadIdx.x;
    const int kb = blockIdx.x & 7;
    const int h  = (blockIdx.x >> 3) & 3;
    const int tz = blockIdx.x >> 5;
    const float* W = tz ? W1 : W0;
    const float* A = tz ? A1 : A0;
    half_t* Wsw = tz ? Wsw1 : Wsw0;
    half_t* Zh  = tz ? Zah1 : Zah0;
    half_t* Zl  = tz ? Zal1 : Zal0;

    for (int i = 0; i < 32; ++i)
        tile[i][t] = W[(size_t)(h * 256 + kb * 32 + i) * 256 + t];
    __syncthreads();

    const int j = t >> 5, lmn = t & 31;
#pragma unroll
    for (int i0 = 0; i0 < 32; i0 += 8) {
        const int ks = 2 * kb + (i0 >> 4);
        const int qq = (i0 >> 3) & 1;
        half_t hb[8];
#pragma unroll
        for (int ii = 0; ii < 8; ++ii) hb[ii] = (half_t)tile[i0 + ii][t];
        size_t off = ((size_t)(h * 16 + ks) * 8 + j) * 512 + (size_t)(32 * qq + lmn) * 8;
        *(half8*)&Wsw[off] = *(half8*)hb;
    }

    if (kb == 0) {
        const float4* Wr = (const float4*)&W[(size_t)(h * 256 + t) * 256];
        const float4* Al = (const float4*)&A[h * 512];
        const float4* Ah = (const float4*)&A[h * 512 + 256];
        float wl = 0.f, wh = 0.f;
        for (int d = 0; d < 64; ++d) {
            float4 wv = Wr[d], a0 = Al[d], a1 = Ah[d];
            wl += wv.x * a0.x + wv.y * a0.y + wv.z * a0.z + wv.w * a0.w;
            wh += wv.x * a1.x + wv.y * a1.y + wv.z * a1.z + wv.w * a1.w;
        }
        half_t hi = (half_t)wl;
        Zh[(2 * h) * 256 + t] = hi;
        Zl[(2 * h) * 256 + t] = (half_t)(wl - (float)hi);
        hi = (half_t)wh;
        Zh[(2 * h + 1) * 256 + t] = hi;
        Zl[(2 * h + 1) * 256 + t] = (half_t)(wh - (float)hi);
        if (h == 0) {
            for (int c = 8; c < 32; ++c) {
                Zh[c * 256 + t] = (half_t)0.f;
                Zl[c * 256 + t] = (half_t)0.f;
            }
        }
    }
}

// ---------------- shared building blocks ----------------

// One 8-element chunk of x -> swizzled hi/lo f16 A-fragments in LDS.
__device__ __forceinline__ void stage_chunk(const float4* __restrict__ xg,
                                            half_t* __restrict__ xsh,
                                            half_t* __restrict__ xsl, int e) {
    int row = e >> 5, cc = e & 31;                 // 32 rows x 32 k-chunks of 8
    float4 v0 = xg[row * 64 + 2 * cc];
    float4 v1 = xg[row * 64 + 2 * cc + 1];
    half_t hb[8], lb[8];
#pragma unroll
    for (int ii = 0; ii < 8; ++ii) {
        float v = (ii < 4) ? (&v0.x)[ii] : (&v1.x)[ii - 4];
        half_t hv = (half_t)v;
        hb[ii] = hv;
        lb[ii] = (half_t)(v - (float)hv);
    }
    int base = ((cc >> 1) * 64 + 32 * (cc & 1) + row) * 16;   // bytes
    *(half8*)((char*)xsh + swz(base)) = *(half8*)hb;
    *(half8*)((char*)xsl + swz(base)) = *(half8*)lb;
}

// z partial over ks in [4w, 4w+4): hi*Bh + lo*Bh + hi*Bl chained into one acc.
__device__ __forceinline__ void z_phase(const half_t* __restrict__ xsh,
                                        const half_t* __restrict__ xsl,
                                        const half_t* __restrict__ Zah,
                                        const half_t* __restrict__ Zal,
                                        float* __restrict__ zrow,   // &zpart[w][0][0], row stride 9
                                        int w, int l, int lm, int q) {
    floatx16 zp = zero16();
#pragma unroll
    for (int kk = 0; kk < 4; ++kk) {
        int ks = 4 * w + kk;
        int ko = lm * 256 + 16 * ks + 8 * q;
        half8 bh = *(const half8*)&Zah[ko];
        half8 bl = *(const half8*)&Zal[ko];
        int ao = (ks * 64 + l) * 16;
        half8 ah = *(const half8*)((const char*)xsh + swz(ao));
        half8 al = *(const half8*)((const char*)xsl + swz(ao));
        zp = MFMA16(ah, bh, zp);
        zp = MFMA16(al, bh, zp);
        zp = MFMA16(ah, bl, zp);
    }
    if (lm < 8) {
#pragma unroll
        for (int r = 0; r < 16; ++r) {
            int row = 4 * q + (r & 3) + 8 * (r >> 2);
            zrow[row * 9 + lm] = zp[r];
        }
    }
}

// Merged hi/lo GEMM for one head over 64 cols (2x 32-col tiles), then the
// attention-weighted row fold. B loaded ONCE (halves B traffic vs 2-pass).
__device__ __forceinline__ void head_gemm(const half_t* __restrict__ xsh,
                                          const half_t* __restrict__ xsl,
                                          const half_t* __restrict__ Bp,
                                          const float* __restrict__ att_h,
                                          int l, int q, float tp[2][2]) {
    floatx16 acc0 = zero16(), acc1 = zero16();
#pragma unroll
    for (int ks = 0; ks < 16; ++ks) {
        half8 b0 = *(const half8*)(Bp + (size_t)ks * 4096);
        half8 b1 = *(const half8*)(Bp + (size_t)ks * 4096 + 512);
        int ao = (ks * 64 + l) * 16;
        half8 ah = *(const half8*)((const char*)xsh + swz(ao));
        half8 al = *(const half8*)((const char*)xsl + swz(ao));
        acc0 = MFMA16(ah, b0, acc0);
        acc0 = MFMA16(al, b0, acc0);
        acc1 = MFMA16(ah, b1, acc1);
        acc1 = MFMA16(al, b1, acc1);
    }
    tp[0][0] = tp[0][1] = tp[1][0] = tp[1][1] = 0.f;
#pragma unroll
    for (int k = 0; k < 4; ++k) {
        float4 a4 = *(const float4*)&att_h[4 * q + 8 * k];
        int g = k >> 1;                            // row>>4 is static: 4q+jj < 8
#pragma unroll
        for (int jj = 0; jj < 4; ++jj) {
            int r = 4 * k + jj;
            float av = (&a4.x)[jj];
            tp[0][g] = fmaf(acc0[r], av, tp[0][g]);
            tp[1][g] = fmaf(acc1[r], av, tp[1][g]);
        }
    }
}

// ---------------- layer 1: 32 rows/block, 256 thr, 4 blocks/CU ----------------
__global__ __launch_bounds__(256, 4) void gat1(
    const float* __restrict__ x, const half_t* __restrict__ Wsw,
    const half_t* __restrict__ Zah, const half_t* __restrict__ Zal,
    float* __restrict__ out) {
    __shared__ __align__(16) half_t xsh[16 * 512];   // 16 KiB
    __shared__ __align__(16) half_t xsl[16 * 512];   // 16 KiB
    __shared__ float zpart[4][32][9];                // 4.5 KiB (pad 9: conflict-free reduce)
    __shared__ __align__(16) float ge_s[4][32];
    __shared__ __align__(16) float att_s[4][32];

    const int t = threadIdx.x;
    const int w = t >> 6, l = t & 63, lm = t & 31, q = (t >> 5) & 1;

    const float4* xg = (const float4*)(x + (size_t)blockIdx.x * 32 * 256);
#pragma unroll
    for (int i = 0; i < 4; ++i) stage_chunk(xg, xsh, xsl, t + 256 * i);
    __syncthreads();

    z_phase(xsh, xsl, Zah, Zal, &zpart[w][0][0], w, l, lm, q);   // 4-way ks-split
    __syncthreads();

    {   // z reduce + double gelu
        int h = t >> 6, r = t & 63;
        if (r < 32) {
            int c0 = 2 * h, c1 = 2 * h + 1, rr = r & ~15;
            float own  = zpart[0][r][c0] + zpart[1][r][c0] + zpart[2][r][c0] + zpart[3][r][c0];
            float root = zpart[0][rr][c1] + zpart[1][rr][c1] + zpart[2][rr][c1] + zpart[3][rr][c1];
            ge_s[h][r] = gelu_exact(gelu_exact(own + root));
        }
    }
    __syncthreads();
    {   // softmax over each 16-row group
        int h = t >> 6, r = t & 63;
        if (r < 32) {
            int g0 = r & ~15;
            float mx = -1e30f;
#pragma unroll
            for (int i = 0; i < 16; ++i) mx = fmaxf(mx, ge_s[h][g0 + i]);
            float sum = 0.f;
#pragma unroll
            for (int i = 0; i < 16; ++i) sum += expf(ge_s[h][g0 + i] - mx);
            att_s[h][r] = expf(ge_s[h][r] - mx) / sum;
        }
    }
    __syncthreads();

    float outp[2][2] = {{0.f, 0.f}, {0.f, 0.f}};
#pragma unroll 1
    for (int h = 0; h < 4; ++h) {
        const half_t* Bp = Wsw + ((size_t)(h * 16) * 8 + 2 * w) * 512 + (size_t)l * 8;
        float tp[2][2];
        head_gemm(xsh, xsl, Bp, &att_s[h][0], l, q, tp);
#pragma unroll
        for (int nt = 0; nt < 2; ++nt)
#pragma unroll
            for (int g = 0; g < 2; ++g) {
                float s = tp[nt][g] + __shfl_xor(tp[nt][g], 32, 64);
                outp[nt][g] += gelu_exact(s);
            }
    }

    if (q == 0) {
#pragma unroll
        for (int g = 0; g < 2; ++g) {
            size_t ro = ((size_t)blockIdx.x * 2 + g) * 256 + 64 * w;
            out[ro + lm]      = 0.25f * outp[0][g];
            out[ro + 32 + lm] = 0.25f * outp[1][g];
        }
    }
}

// ---------------- layer 2: 32 rows/block, 1024 thr (4 heads x 4 strips), 256 blocks = 1 round ----------------
__global__ __launch_bounds__(1024, 1) void gat2(
    const float* __restrict__ x, const half_t* __restrict__ Wsw,
    const half_t* __restrict__ Zah, const half_t* __restrict__ Zal,
    float* __restrict__ out) {
    __shared__ __align__(16) half_t xsh[16 * 512];
    __shared__ __align__(16) half_t xsl[16 * 512];
    __shared__ float zpart[4][32][9];
    __shared__ __align__(16) float ge_s[4][32];
    __shared__ __align__(16) float att_s[4][32];
    __shared__ float outp_s[4][2][256];              // per-head partials, 8 KiB

    const int t = threadIdx.x;
    const int w = t >> 6, l = t & 63, lm = t & 31, q = (t >> 5) & 1;

    const float4* xg = (const float4*)(x + (size_t)blockIdx.x * 32 * 256);
    stage_chunk(xg, xsh, xsl, t);                    // 1024 threads = exactly one chunk each
    __syncthreads();

    if (w < 4) z_phase(xsh, xsl, Zah, Zal, &zpart[w][0][0], w, l, lm, q);
    __syncthreads();

    if (t < 128) {
        int h = t >> 5, r = t & 31;
        int c0 = 2 * h, c1 = 2 * h + 1, rr = r & ~15;
        float own  = zpart[0][r][c0] + zpart[1][r][c0] + zpart[2][r][c0] + zpart[3][r][c0];
        float root = zpart[0][rr][c1] + zpart[1][rr][c1] + zpart[2][rr][c1] + zpart[3][rr][c1];
        ge_s[h][r] = gelu_exact(gelu_exact(own + root));
    }
    __syncthreads();
    if (t < 128) {
        int h = t >> 5, r = t & 31;
        int g0 = r & ~15;
        float mx = -1e30f;
#pragma unroll
        for (int i = 0; i < 16; ++i) mx = fmaxf(mx, ge_s[h][g0 + i]);
        float sum = 0.f;
#pragma unroll
        for (int i = 0; i < 16; ++i) sum += expf(ge_s[h][g0 + i] - mx);
        att_s[h][r] = expf(ge_s[h][r] - mx) / sum;
    }
    __syncthreads();

    const int head = w >> 2, strip = w & 3;
    const half_t* Bp = Wsw + ((size_t)(head * 16) * 8 + 2 * strip) * 512 + (size_t)l * 8;
    float tp[2][2];
    head_gemm(xsh, xsl, Bp, &att_s[head][0], l, q, tp);
#pragma unroll
    for (int nt = 0; nt < 2; ++nt)
#pragma unroll
        for (int g = 0; g < 2; ++g) {
            float s = tp[nt][g] + __shfl_xor(tp[nt][g], 32, 64);
            if (q == 0) outp_s[head][g][64 * strip + 32 * nt + lm] = gelu_exact(s);
        }
    __syncthreads();

    if (t < 512) {
        int g = t >> 8, col = t & 255;
        float s = outp_s[0][g][col] + outp_s[1][g][col] + outp_s[2][g][col] + outp_s[3][g][col];
        out[((size_t)blockIdx.x * 2 + g) * 256 + col] = 0.25f * s;
    }
}

extern "C" void kernel_launch(void* const* d_in, const int* in_sizes, int n_in,
                              void* d_out, int out_size, void* d_ws, size_t ws_size,
                              hipStream_t stream) {
    const float* x  = (const float*)d_in[0];
    const float* W0 = (const float*)d_in[1];
    const float* A0 = (const float*)d_in[2];
    const float* W1 = (const float*)d_in[3];
    const float* A1 = (const float*)d_in[4];

    char* ws = (char*)d_ws;
    float*  y1   = (float*)ws;                  // 8 MiB: [8192][256]
    half_t* Wsw0 = (half_t*)(ws + 8388608);     // 512 KiB
    half_t* Wsw1 = (half_t*)(ws + 8912896);     // 512 KiB
    half_t* Zah0 = (half_t*)(ws + 9437184);     // 16 KiB each
    half_t* Zal0 = (half_t*)(ws + 9453568);
    half_t* Zah1 = (half_t*)(ws + 9469952);
    half_t* Zal1 = (half_t*)(ws + 9486336);

    prep<<<64, 256, 0, stream>>>(W0, A0, W1, A1, Wsw0, Wsw1, Zah0, Zal0, Zah1, Zal1);
    gat1<<<4096, 256, 0, stream>>>(x, Wsw0, Zah0, Zal0, y1);
    gat2<<<256, 1024, 0, stream>>>(y1, Wsw1, Zah1, Zal1, (float*)d_out);
}

// Round 2
// 443.806 us; speedup vs baseline: 1.0828x; 1.0828x over previous
//
#include <hip/hip_runtime.h>
#include <math.h>

typedef _Float16 half_t;
typedef __attribute__((ext_vector_type(8))) _Float16 half8;
typedef __attribute__((ext_vector_type(16))) float floatx16;

__device__ __forceinline__ float gelu_exact(float v) {
    return 0.5f * v * (1.0f + erff(v * 0.7071067811865476f));
}

__device__ __forceinline__ floatx16 zero16() {
    floatx16 z;
#pragma unroll
    for (int i = 0; i < 16; ++i) z[i] = 0.f;
    return z;
}

// LDS byte-offset swizzle (validated round 1: staging-write conflicts 7.5M -> 0,
// reads stay conflict-free). Only needed when staging from strided fp32 x.
__device__ __forceinline__ int swz(int b) { return b ^ (((b >> 9) & 7) << 4); }

template <bool SWZ>
__device__ __forceinline__ half8 lds_frag(const half_t* p, int byteoff) {
    if (SWZ) byteoff = swz(byteoff);
    return *(const half8*)((const char*)p + byteoff);
}

#define MFMA16(a, b, c) __builtin_amdgcn_mfma_f32_32x32x16_f16((a), (b), (c), 0, 0, 0)

// ---------------- prep ---------------- (unchanged; layout validated)
__global__ __launch_bounds__(256) void prep(const float* __restrict__ W0,
                                            const float* __restrict__ A0,
                                            const float* __restrict__ W1,
                                            const float* __restrict__ A1,
                                            half_t* __restrict__ Wsw0, half_t* __restrict__ Wsw1,
                                            half_t* __restrict__ Zah0, half_t* __restrict__ Zal0,
                                            half_t* __restrict__ Zah1, half_t* __restrict__ Zal1) {
    __shared__ float tile[32][257];
    const int t  = threadIdx.x;
    const int kb = blockIdx.x & 7;
    const int h  = (blockIdx.x >> 3) & 3;
    const int tz = blockIdx.x >> 5;
    const float* W = tz ? W1 : W0;
    const float* A = tz ? A1 : A0;
    half_t* Wsw = tz ? Wsw1 : Wsw0;
    half_t* Zh  = tz ? Zah1 : Zah0;
    half_t* Zl  = tz ? Zal1 : Zal0;

    for (int i = 0; i < 32; ++i)
        tile[i][t] = W[(size_t)(h * 256 + kb * 32 + i) * 256 + t];
    __syncthreads();

    const int j = t >> 5, lmn = t & 31;
#pragma unroll
    for (int i0 = 0; i0 < 32; i0 += 8) {
        const int ks = 2 * kb + (i0 >> 4);
        const int qq = (i0 >> 3) & 1;
        half_t hb[8];
#pragma unroll
        for (int ii = 0; ii < 8; ++ii) hb[ii] = (half_t)tile[i0 + ii][t];
        size_t off = ((size_t)(h * 16 + ks) * 8 + j) * 512 + (size_t)(32 * qq + lmn) * 8;
        *(half8*)&Wsw[off] = *(half8*)hb;
    }

    if (kb == 0) {
        const float4* Wr = (const float4*)&W[(size_t)(h * 256 + t) * 256];
        const float4* Al = (const float4*)&A[h * 512];
        const float4* Ah = (const float4*)&A[h * 512 + 256];
        float wl = 0.f, wh = 0.f;
        for (int d = 0; d < 64; ++d) {
            float4 wv = Wr[d], a0 = Al[d], a1 = Ah[d];
            wl += wv.x * a0.x + wv.y * a0.y + wv.z * a0.z + wv.w * a0.w;
            wh += wv.x * a1.x + wv.y * a1.y + wv.z * a1.z + wv.w * a1.w;
        }
        half_t hi = (half_t)wl;
        Zh[(2 * h) * 256 + t] = hi;
        Zl[(2 * h) * 256 + t] = (half_t)(wl - (float)hi);
        hi = (half_t)wh;
        Zh[(2 * h + 1) * 256 + t] = hi;
        Zl[(2 * h + 1) * 256 + t] = (half_t)(wh - (float)hi);
        if (h == 0) {
            for (int c = 8; c < 32; ++c) {
                Zh[c * 256 + t] = (half_t)0.f;
                Zl[c * 256 + t] = (half_t)0.f;
            }
        }
    }
}

// ---------------- shared building blocks ----------------

// fp32 x chunk -> swizzled hi/lo f16 A-fragments in LDS (gat1 staging).
__device__ __forceinline__ void stage_chunk(const float4* __restrict__ xg,
                                            half_t* __restrict__ xsh,
                                            half_t* __restrict__ xsl, int e) {
    int row = e >> 5, cc = e & 31;
    float4 v0 = xg[row * 64 + 2 * cc];
    float4 v1 = xg[row * 64 + 2 * cc + 1];
    half_t hb[8], lb[8];
#pragma unroll
    for (int ii = 0; ii < 8; ++ii) {
        float v = (ii < 4) ? (&v0.x)[ii] : (&v1.x)[ii - 4];
        half_t hv = (half_t)v;
        hb[ii] = hv;
        lb[ii] = (half_t)(v - (float)hv);
    }
    int m = row >> 5, r31 = row & 31, ks = cc >> 1, kq = cc & 1;
    int base = ((m * 16 + ks) * 64 + 32 * kq + r31) * 16;   // bytes
    *(half8*)((char*)xsh + swz(base)) = *(half8*)hb;
    *(half8*)((char*)xsl + swz(base)) = *(half8*)lb;
}

// z partial over ks in [4w, 4w+4): hi*Bh + lo*Bh + hi*Bl chained into one acc.
template <int MT, bool SWZ>
__device__ __forceinline__ void z_phase(const half_t* __restrict__ xsh,
                                        const half_t* __restrict__ xsl,
                                        const half_t* __restrict__ Zah,
                                        const half_t* __restrict__ Zal,
                                        float* __restrict__ zrow,   // row stride 9
                                        int w, int l, int lm, int q) {
    floatx16 zp[MT];
#pragma unroll
    for (int mt = 0; mt < MT; ++mt) zp[mt] = zero16();
#pragma unroll
    for (int kk = 0; kk < 4; ++kk) {
        int ks = 4 * w + kk;
        int ko = lm * 256 + 16 * ks + 8 * q;
        half8 bh = *(const half8*)&Zah[ko];
        half8 bl = *(const half8*)&Zal[ko];
#pragma unroll
        for (int mt = 0; mt < MT; ++mt) {
            int ao = ((mt * 16 + ks) * 64 + l) * 16;
            half8 ah = lds_frag<SWZ>(xsh, ao);
            half8 al = lds_frag<SWZ>(xsl, ao);
            zp[mt] = MFMA16(ah, bh, zp[mt]);
            zp[mt] = MFMA16(al, bh, zp[mt]);
            zp[mt] = MFMA16(ah, bl, zp[mt]);
        }
    }
    if (lm < 8) {
#pragma unroll
        for (int mt = 0; mt < MT; ++mt)
#pragma unroll
            for (int r = 0; r < 16; ++r) {
                int row = 32 * mt + 4 * q + (r & 3) + 8 * (r >> 2);
                zrow[row * 9 + lm] = zp[mt][r];
            }
    }
}

// ---------------- layer 1: 64 rows/block, 256 thr, 2048 blocks, 2 blk/CU ----------------
// Round-0 geometry (proven 75 MB FETCH) + merged hi/lo pass (halves B loads)
// + swizzled staging (0 bank conflicts) + 4-way-parallel z phase.
// Emits y1 as hi/lo f16 directly in gat2's A-fragment layout.
__global__ __launch_bounds__(256, 2) void gat1(
    const float* __restrict__ x, const half_t* __restrict__ Wsw,
    const half_t* __restrict__ Zah, const half_t* __restrict__ Zal,
    half_t* __restrict__ y1h, half_t* __restrict__ y1l) {
    __shared__ __align__(16) half_t xsh[32 * 512];   // 32 KiB
    __shared__ __align__(16) half_t xsl[32 * 512];   // 32 KiB
    __shared__ float zpart[4][64][9];                // 9 KiB
    __shared__ __align__(16) float ge_s[4][64];
    __shared__ __align__(16) float att_s[4][64];

    const int t = threadIdx.x;
    const int w = t >> 6, l = t & 63, lm = t & 31, q = (t >> 5) & 1;

    const float4* xg = (const float4*)(x + (size_t)blockIdx.x * 64 * 256);
#pragma unroll
    for (int i = 0; i < 8; ++i) stage_chunk(xg, xsh, xsl, t + 256 * i);
    __syncthreads();

    z_phase<2, true>(xsh, xsl, Zah, Zal, &zpart[w][0][0], w, l, lm, q);
    __syncthreads();

    {   // z reduce + double gelu (all 256 threads: 4 heads x 64 rows)
        int h = t >> 6, r = t & 63;
        int c0 = 2 * h, c1 = 2 * h + 1, rr = r & ~15;
        float own  = zpart[0][r][c0] + zpart[1][r][c0] + zpart[2][r][c0] + zpart[3][r][c0];
        float root = zpart[0][rr][c1] + zpart[1][rr][c1] + zpart[2][rr][c1] + zpart[3][rr][c1];
        ge_s[h][r] = gelu_exact(gelu_exact(own + root));
    }
    __syncthreads();
    {   // softmax over each 16-row group
        int h = t >> 6, r = t & 63;
        int g0 = r & ~15;
        float mx = -1e30f;
#pragma unroll
        for (int i = 0; i < 16; ++i) mx = fmaxf(mx, ge_s[h][g0 + i]);
        float sum = 0.f;
#pragma unroll
        for (int i = 0; i < 16; ++i) sum += expf(ge_s[h][g0 + i] - mx);
        att_s[h][r] = expf(ge_s[h][r] - mx) / sum;
    }
    __syncthreads();

    float outp[2][4];
#pragma unroll
    for (int nt = 0; nt < 2; ++nt)
#pragma unroll
        for (int g = 0; g < 4; ++g) outp[nt][g] = 0.f;

#pragma unroll 1
    for (int h = 0; h < 4; ++h) {
        const half_t* Bp = Wsw + ((size_t)(h * 16) * 8 + 2 * w) * 512 + (size_t)l * 8;
        floatx16 acc[2][2];
        acc[0][0] = zero16(); acc[0][1] = zero16();
        acc[1][0] = zero16(); acc[1][1] = zero16();
#pragma unroll
        for (int ks = 0; ks < 16; ++ks) {
            half8 b0 = *(const half8*)(Bp + (size_t)ks * 4096);
            half8 b1 = *(const half8*)(Bp + (size_t)ks * 4096 + 512);
#pragma unroll
            for (int mt = 0; mt < 2; ++mt) {
                int ao = ((mt * 16 + ks) * 64 + l) * 16;
                half8 ah = lds_frag<true>(xsh, ao);
                half8 al = lds_frag<true>(xsl, ao);
                acc[mt][0] = MFMA16(ah, b0, acc[mt][0]);
                acc[mt][0] = MFMA16(al, b0, acc[mt][0]);
                acc[mt][1] = MFMA16(ah, b1, acc[mt][1]);
                acc[mt][1] = MFMA16(al, b1, acc[mt][1]);
            }
        }

        float tp[2][4];
#pragma unroll
        for (int nt = 0; nt < 2; ++nt)
#pragma unroll
            for (int g = 0; g < 4; ++g) tp[nt][g] = 0.f;
#pragma unroll
        for (int mt = 0; mt < 2; ++mt)
#pragma unroll
            for (int k = 0; k < 4; ++k) {
                float4 a4 = *(const float4*)&att_s[h][32 * mt + 4 * q + 8 * k];
#pragma unroll
                for (int jj = 0; jj < 4; ++jj) {
                    int r = 4 * k + jj;
                    int row = 32 * mt + 4 * q + 8 * k + jj;
                    int g = row >> 4;
                    float av = (&a4.x)[jj];
                    tp[0][g] = fmaf(acc[mt][0][r], av, tp[0][g]);
                    tp[1][g] = fmaf(acc[mt][1][r], av, tp[1][g]);
                }
            }
#pragma unroll
        for (int nt = 0; nt < 2; ++nt)
#pragma unroll
            for (int g = 0; g < 4; ++g) {
                float s = tp[nt][g] + __shfl_xor(tp[nt][g], 32, 64);
                outp[nt][g] += gelu_exact(s);
            }
    }

    // ---- store y1 directly as hi/lo f16 A-fragments for gat2 ----
    // value at (row r = 4*bI+g, col c = 64w+32nt+lm) -> frag offset
    // ((r>>5)*16 + (c>>4))*64*8 + 32*((c>>3)&1)*8 + (r&31)*8 + (c&7)
    if (q == 0) {
#pragma unroll
        for (int nt = 0; nt < 2; ++nt)
#pragma unroll
            for (int g = 0; g < 4; ++g) {
                float v = 0.25f * outp[nt][g];
                half_t hv = (half_t)v;
                half_t lv = (half_t)(v - (float)hv);
                int r  = 4 * (int)blockIdx.x + g;
                int ks = 4 * w + 2 * nt + (lm >> 4);
                int sub = (lm >> 3) & 1;
                size_t off = (((size_t)((r >> 5) * 16 + ks) * 64) + 32 * sub + (r & 31)) * 8 + (lm & 7);
                y1h[off] = hv;
                y1l[off] = lv;
            }
    }
}

// ---------------- layer 2: 32 rows/block, 1024 thr, 256 blocks ----------------
// Staging is now a straight coalesced b128 copy (frag layout precomputed by gat1):
// no convert, no swizzle, conflict-free reads at stride 16.
__global__ __launch_bounds__(1024, 1) void gat2(
    const half_t* __restrict__ y1h, const half_t* __restrict__ y1l,
    const half_t* __restrict__ Wsw,
    const half_t* __restrict__ Zah, const half_t* __restrict__ Zal,
    float* __restrict__ out) {
    __shared__ __align__(16) half_t xsh[16 * 512];
    __shared__ __align__(16) half_t xsl[16 * 512];
    __shared__ float zpart[4][32][9];
    __shared__ __align__(16) float ge_s[4][32];
    __shared__ __align__(16) float att_s[4][32];
    __shared__ float outp_s[4][2][256];

    const int t = threadIdx.x;
    const int w = t >> 6, l = t & 63, lm = t & 31, q = (t >> 5) & 1;

    {
        size_t gb = (size_t)blockIdx.x * 8192 + 8 * t;
        *(half8*)&xsh[8 * t] = *(const half8*)&y1h[gb];
        *(half8*)&xsl[8 * t] = *(const half8*)&y1l[gb];
    }
    __syncthreads();

    if (w < 4) z_phase<1, false>(xsh, xsl, Zah, Zal, &zpart[w][0][0], w, l, lm, q);
    __syncthreads();

    if (t < 128) {
        int h = t >> 5, r = t & 31;
        int c0 = 2 * h, c1 = 2 * h + 1, rr = r & ~15;
        float own  = zpart[0][r][c0] + zpart[1][r][c0] + zpart[2][r][c0] + zpart[3][r][c0];
        float root = zpart[0][rr][c1] + zpart[1][rr][c1] + zpart[2][rr][c1] + zpart[3][rr][c1];
        ge_s[h][r] = gelu_exact(gelu_exact(own + root));
    }
    __syncthreads();
    if (t < 128) {
        int h = t >> 5, r = t & 31;
        int g0 = r & ~15;
        float mx = -1e30f;
#pragma unroll
        for (int i = 0; i < 16; ++i) mx = fmaxf(mx, ge_s[h][g0 + i]);
        float sum = 0.f;
#pragma unroll
        for (int i = 0; i < 16; ++i) sum += expf(ge_s[h][g0 + i] - mx);
        att_s[h][r] = expf(ge_s[h][r] - mx) / sum;
    }
    __syncthreads();

    const int head = w >> 2, strip = w & 3;
    const half_t* Bp = Wsw + ((size_t)(head * 16) * 8 + 2 * strip) * 512 + (size_t)l * 8;

    floatx16 acc0 = zero16(), acc1 = zero16();
#pragma unroll
    for (int ks = 0; ks < 16; ++ks) {
        half8 b0 = *(const half8*)(Bp + (size_t)ks * 4096);
        half8 b1 = *(const half8*)(Bp + (size_t)ks * 4096 + 512);
        int ao = (ks * 64 + l) * 16;
        half8 ah = lds_frag<false>(xsh, ao);
        half8 al = lds_frag<false>(xsl, ao);
        acc0 = MFMA16(ah, b0, acc0);
        acc0 = MFMA16(al, b0, acc0);
        acc1 = MFMA16(ah, b1, acc1);
        acc1 = MFMA16(al, b1, acc1);
    }
    float tp[2][2];
    tp[0][0] = tp[0][1] = tp[1][0] = tp[1][1] = 0.f;
#pragma unroll
    for (int k = 0; k < 4; ++k) {
        float4 a4 = *(const float4*)&att_s[head][4 * q + 8 * k];
        int g = k >> 1;
#pragma unroll
        for (int jj = 0; jj < 4; ++jj) {
            int r = 4 * k + jj;
            float av = (&a4.x)[jj];
            tp[0][g] = fmaf(acc0[r], av, tp[0][g]);
            tp[1][g] = fmaf(acc1[r], av, tp[1][g]);
        }
    }
#pragma unroll
    for (int nt = 0; nt < 2; ++nt)
#pragma unroll
        for (int g = 0; g < 2; ++g) {
            float s = tp[nt][g] + __shfl_xor(tp[nt][g], 32, 64);
            if (q == 0) outp_s[head][g][64 * strip + 32 * nt + lm] = gelu_exact(s);
        }
    __syncthreads();

    if (t < 512) {
        int g = t >> 8, col = t & 255;
        float s = outp_s[0][g][col] + outp_s[1][g][col] + outp_s[2][g][col] + outp_s[3][g][col];
        out[((size_t)blockIdx.x * 2 + g) * 256 + col] = 0.25f * s;
    }
}

extern "C" void kernel_launch(void* const* d_in, const int* in_sizes, int n_in,
                              void* d_out, int out_size, void* d_ws, size_t ws_size,
                              hipStream_t stream) {
    const float* x  = (const float*)d_in[0];
    const float* W0 = (const float*)d_in[1];
    const float* A0 = (const float*)d_in[2];
    const float* W1 = (const float*)d_in[3];
    const float* A1 = (const float*)d_in[4];

    char* ws = (char*)d_ws;
    half_t* y1h  = (half_t*)ws;                 // 4 MiB
    half_t* y1l  = (half_t*)(ws + 4194304);     // 4 MiB
    half_t* Wsw0 = (half_t*)(ws + 8388608);     // 512 KiB
    half_t* Wsw1 = (half_t*)(ws + 8912896);     // 512 KiB
    half_t* Zah0 = (half_t*)(ws + 9437184);     // 16 KiB each
    half_t* Zal0 = (half_t*)(ws + 9453568);
    half_t* Zah1 = (half_t*)(ws + 9469952);
    half_t* Zal1 = (half_t*)(ws + 9486336);

    prep<<<64, 256, 0, stream>>>(W0, A0, W1, A1, Wsw0, Wsw1, Zah0, Zal0, Zah1, Zal1);
    gat1<<<2048, 256, 0, stream>>>(x, Wsw0, Zah0, Zal0, y1h, y1l);
    gat2<<<256, 1024, 0, stream>>>(y1h, y1l, Wsw1, Zah1, Zal1, (float*)d_out);
}

// Round 3
// 372.863 us; speedup vs baseline: 1.2889x; 1.1903x over previous
//
#include <hip/hip_runtime.h>
#include <math.h>

typedef _Float16 half_t;
typedef __attribute__((ext_vector_type(8))) _Float16 half8;
typedef __attribute__((ext_vector_type(16))) float floatx16;

__device__ __forceinline__ float gelu_exact(float v) {
    return 0.5f * v * (1.0f + erff(v * 0.7071067811865476f));
}

__device__ __forceinline__ floatx16 zero16() {
    floatx16 z;
#pragma unroll
    for (int i = 0; i < 16; ++i) z[i] = 0.f;
    return z;
}

// LDS byte-offset swizzle (validated: staging-write conflicts -> 0, reads stay
// conflict-free). Used in gat2 only this round (gat1 is the untouched control).
__device__ __forceinline__ int swz(int b) { return b ^ (((b >> 9) & 7) << 4); }

template <bool SWZ>
__device__ __forceinline__ half8 lds_frag(const half_t* p, int byteoff) {
    if (SWZ) byteoff = swz(byteoff);
    return *(const half8*)((const char*)p + byteoff);
}

#define MFMA16(a, b, c) __builtin_amdgcn_mfma_f32_32x32x16_f16((a), (b), (c), 0, 0, 0)

// ---------------- prep ---------------- (unchanged; layout validated)
__global__ __launch_bounds__(256) void prep(const float* __restrict__ W0,
                                            const float* __restrict__ A0,
                                            const float* __restrict__ W1,
                                            const float* __restrict__ A1,
                                            half_t* __restrict__ Wsw0, half_t* __restrict__ Wsw1,
                                            half_t* __restrict__ Zah0, half_t* __restrict__ Zal0,
                                            half_t* __restrict__ Zah1, half_t* __restrict__ Zal1) {
    __shared__ float tile[32][257];
    const int t  = threadIdx.x;
    const int kb = blockIdx.x & 7;
    const int h  = (blockIdx.x >> 3) & 3;
    const int tz = blockIdx.x >> 5;
    const float* W = tz ? W1 : W0;
    const float* A = tz ? A1 : A0;
    half_t* Wsw = tz ? Wsw1 : Wsw0;
    half_t* Zh  = tz ? Zah1 : Zah0;
    half_t* Zl  = tz ? Zal1 : Zal0;

    for (int i = 0; i < 32; ++i)
        tile[i][t] = W[(size_t)(h * 256 + kb * 32 + i) * 256 + t];
    __syncthreads();

    const int j = t >> 5, lmn = t & 31;
#pragma unroll
    for (int i0 = 0; i0 < 32; i0 += 8) {
        const int ks = 2 * kb + (i0 >> 4);
        const int qq = (i0 >> 3) & 1;
        half_t hb[8];
#pragma unroll
        for (int ii = 0; ii < 8; ++ii) hb[ii] = (half_t)tile[i0 + ii][t];
        size_t off = ((size_t)(h * 16 + ks) * 8 + j) * 512 + (size_t)(32 * qq + lmn) * 8;
        *(half8*)&Wsw[off] = *(half8*)hb;
    }

    if (kb == 0) {
        const float4* Wr = (const float4*)&W[(size_t)(h * 256 + t) * 256];
        const float4* Al = (const float4*)&A[h * 512];
        const float4* Ah = (const float4*)&A[h * 512 + 256];
        float wl = 0.f, wh = 0.f;
        for (int d = 0; d < 64; ++d) {
            float4 wv = Wr[d], a0 = Al[d], a1 = Ah[d];
            wl += wv.x * a0.x + wv.y * a0.y + wv.z * a0.z + wv.w * a0.w;
            wh += wv.x * a1.x + wv.y * a1.y + wv.z * a1.z + wv.w * a1.w;
        }
        half_t hi = (half_t)wl;
        Zh[(2 * h) * 256 + t] = hi;
        Zl[(2 * h) * 256 + t] = (half_t)(wl - (float)hi);
        hi = (half_t)wh;
        Zh[(2 * h + 1) * 256 + t] = hi;
        Zl[(2 * h + 1) * 256 + t] = (half_t)(wh - (float)hi);
        if (h == 0) {
            for (int c = 8; c < 32; ++c) {
                Zh[c * 256 + t] = (half_t)0.f;
                Zl[c * 256 + t] = (half_t)0.f;
            }
        }
    }
}

// ---------------- layer 1: EXACT round-0 kernel (control arm) ----------------
// Proven: 187 us, FETCH 75 MB, WRITE 12 MB, MfmaUtil 35%.
template <int GROUPS>
__global__ __launch_bounds__(256, 2) void gat_layer(
    const float* __restrict__ x,
    const half_t* __restrict__ Wsw,
    const half_t* __restrict__ Zah, const half_t* __restrict__ Zal,
    float* __restrict__ out) {
    constexpr int ROWS = GROUPS * 16;
    constexpr int MT   = ROWS / 32;

    __shared__ half_t xsh[MT * 16 * 512];
    __shared__ half_t xsl[MT * 16 * 512];
    __shared__ float zlo_s[4][ROWS];
    __shared__ float zhi_s[4][ROWS];
    __shared__ float ge_s[4][ROWS];
    __shared__ float att_s[4][ROWS];

    const int t  = threadIdx.x;
    const int w  = t >> 6;
    const int l  = t & 63;
    const int lm = t & 31;
    const int q  = (t >> 5) & 1;

    {
        const float4* xg = (const float4*)(x + (size_t)blockIdx.x * ROWS * 256);
#pragma unroll
        for (int i = 0; i < ROWS / 8; ++i) {
            int e = t + 256 * i;
            int row = e >> 5, cc = e & 31;
            float4 v0 = xg[row * 64 + 2 * cc];
            float4 v1 = xg[row * 64 + 2 * cc + 1];
            half_t hb[8], lb[8];
            const float* vf = &v0.x;
#pragma unroll
            for (int ii = 0; ii < 8; ++ii) {
                float v = (ii < 4) ? vf[ii] : (&v1.x)[ii - 4];
                half_t hv = (half_t)v;
                hb[ii] = hv;
                lb[ii] = (half_t)(v - (float)hv);
            }
            int m = row >> 5, r31 = row & 31, ks = cc >> 1, kq = cc & 1;
            int base = ((m * 16 + ks) * 64 + 32 * kq + r31) * 8;
            *(half8*)&xsh[base] = *(half8*)hb;
            *(half8*)&xsl[base] = *(half8*)lb;
        }
    }
    __syncthreads();

    if (w == 0) {
        floatx16 zm[MT], zc[MT];
#pragma unroll
        for (int mt = 0; mt < MT; ++mt) { zm[mt] = zero16(); zc[mt] = zero16(); }
#pragma unroll 4
        for (int ks = 0; ks < 16; ++ks) {
            const int ko = lm * 256 + 16 * ks + 8 * q;
            half8 bh = *(const half8*)&Zah[ko];
            half8 bl = *(const half8*)&Zal[ko];
#pragma unroll
            for (int mt = 0; mt < MT; ++mt) {
                half8 a  = *(const half8*)&xsh[((mt * 16 + ks) * 64 + l) * 8];
                half8 al = *(const half8*)&xsl[((mt * 16 + ks) * 64 + l) * 8];
                zm[mt] = MFMA16(a, bh, zm[mt]);
                zc[mt] = MFMA16(al, bh, zc[mt]);
                zc[mt] = MFMA16(a, bl, zc[mt]);
            }
        }
        if (lm < 8) {
            int h = lm >> 1;
            float* dst = (lm & 1) ? &zhi_s[h][0] : &zlo_s[h][0];
#pragma unroll
            for (int mt = 0; mt < MT; ++mt)
#pragma unroll
                for (int r = 0; r < 16; ++r) {
                    int row = 32 * mt + 4 * q + (r & 3) + 8 * (r >> 2);
                    dst[row] = zm[mt][r] + zc[mt][r];
                }
        }
    }
    __syncthreads();

    {
        int h = t >> 6, r = t & 63;
        if (r < ROWS) {
            float z = zlo_s[h][r] + zhi_s[h][r & ~15];
            ge_s[h][r] = gelu_exact(gelu_exact(z));
        }
    }
    __syncthreads();
    {
        int h = t >> 6, r = t & 63;
        if (r < ROWS) {
            int g0 = r & ~15;
            float mx = -1e30f;
#pragma unroll
            for (int i = 0; i < 16; ++i) mx = fmaxf(mx, ge_s[h][g0 + i]);
            float s = 0.f;
#pragma unroll
            for (int i = 0; i < 16; ++i) s += expf(ge_s[h][g0 + i] - mx);
            att_s[h][r] = expf(ge_s[h][r] - mx) / s;
        }
    }
    __syncthreads();

    float outp[2][GROUPS];
#pragma unroll
    for (int nt = 0; nt < 2; ++nt)
#pragma unroll
        for (int g = 0; g < GROUPS; ++g) outp[nt][g] = 0.f;

#pragma unroll 1
    for (int h = 0; h < 4; ++h) {
        float tp[2][GROUPS];
#pragma unroll
        for (int nt = 0; nt < 2; ++nt)
#pragma unroll
            for (int g = 0; g < GROUPS; ++g) tp[nt][g] = 0.f;

        const half_t* Bp = Wsw + ((size_t)(h * 16) * 8 + 2 * w) * 512 + (size_t)l * 8;

#pragma unroll 1
        for (int pass = 0; pass < 2; ++pass) {
            const half_t* Xp = pass ? xsl : xsh;
            floatx16 acc[MT][2];
#pragma unroll
            for (int mt = 0; mt < MT; ++mt) { acc[mt][0] = zero16(); acc[mt][1] = zero16(); }

#pragma unroll
            for (int ks = 0; ks < 16; ++ks) {
                half8 b0 = *(const half8*)(Bp + (size_t)ks * 4096);
                half8 b1 = *(const half8*)(Bp + (size_t)ks * 4096 + 512);
#pragma unroll
                for (int mt = 0; mt < MT; ++mt) {
                    half8 a = *(const half8*)&Xp[((mt * 16 + ks) * 64 + l) * 8];
                    acc[mt][0] = MFMA16(a, b0, acc[mt][0]);
                    acc[mt][1] = MFMA16(a, b1, acc[mt][1]);
                }
            }

#pragma unroll
            for (int mt = 0; mt < MT; ++mt)
#pragma unroll
                for (int k = 0; k < 4; ++k) {
                    float4 a4 = *(const float4*)&att_s[h][32 * mt + 4 * q + 8 * k];
#pragma unroll
                    for (int jj = 0; jj < 4; ++jj) {
                        int r = 4 * k + jj;
                        int row = 32 * mt + 4 * q + 8 * k + jj;
                        int g = row >> 4;
                        float av = (&a4.x)[jj];
                        tp[0][g] = fmaf(acc[mt][0][r], av, tp[0][g]);
                        tp[1][g] = fmaf(acc[mt][1][r], av, tp[1][g]);
                    }
                }
        }

#pragma unroll
        for (int nt = 0; nt < 2; ++nt)
#pragma unroll
            for (int g = 0; g < GROUPS; ++g) {
                float s = tp[nt][g] + __shfl_xor(tp[nt][g], 32, 64);
                outp[nt][g] += gelu_exact(s);
            }
    }

    if (q == 0) {
#pragma unroll
        for (int g = 0; g < GROUPS; ++g) {
            size_t ro = ((size_t)blockIdx.x * GROUPS + g) * 256 + 64 * w;
            out[ro + lm]      = 0.25f * outp[0][g];
            out[ro + 32 + lm] = 0.25f * outp[1][g];
        }
    }
}

// ---------------- gat2 building blocks (treatment arm) ----------------

// fp32 chunk -> swizzled hi/lo f16 A-fragments in LDS (32-row tile).
__device__ __forceinline__ void stage_chunk(const float4* __restrict__ xg,
                                            half_t* __restrict__ xsh,
                                            half_t* __restrict__ xsl, int e) {
    int row = e >> 5, cc = e & 31;
    float4 v0 = xg[row * 64 + 2 * cc];
    float4 v1 = xg[row * 64 + 2 * cc + 1];
    half_t hb[8], lb[8];
#pragma unroll
    for (int ii = 0; ii < 8; ++ii) {
        float v = (ii < 4) ? (&v0.x)[ii] : (&v1.x)[ii - 4];
        half_t hv = (half_t)v;
        hb[ii] = hv;
        lb[ii] = (half_t)(v - (float)hv);
    }
    int base = ((cc >> 1) * 64 + 32 * (cc & 1) + row) * 16;   // bytes
    *(half8*)((char*)xsh + swz(base)) = *(half8*)hb;
    *(half8*)((char*)xsl + swz(base)) = *(half8*)lb;
}

// z partial over ks in [4w, 4w+4): hi*Bh + lo*Bh + hi*Bl chained into one acc.
__device__ __forceinline__ void z_phase(const half_t* __restrict__ xsh,
                                        const half_t* __restrict__ xsl,
                                        const half_t* __restrict__ Zah,
                                        const half_t* __restrict__ Zal,
                                        float* __restrict__ zrow,   // row stride 9
                                        int w, int l, int lm, int q) {
    floatx16 zp = zero16();
#pragma unroll
    for (int kk = 0; kk < 4; ++kk) {
        int ks = 4 * w + kk;
        int ko = lm * 256 + 16 * ks + 8 * q;
        half8 bh = *(const half8*)&Zah[ko];
        half8 bl = *(const half8*)&Zal[ko];
        int ao = (ks * 64 + l) * 16;
        half8 ah = lds_frag<true>(xsh, ao);
        half8 al = lds_frag<true>(xsl, ao);
        zp = MFMA16(ah, bh, zp);
        zp = MFMA16(al, bh, zp);
        zp = MFMA16(ah, bl, zp);
    }
    if (lm < 8) {
#pragma unroll
        for (int r = 0; r < 16; ++r) {
            int row = 4 * q + (r & 3) + 8 * (r >> 2);
            zrow[row * 9 + lm] = zp[r];
        }
    }
}

// ---------------- layer 2: 32 rows/block, 512 thr (4 heads x 2 strips), 256 blocks ----------------
// Low-pressure: (512,1) -> 2 waves/SIMD -> 256-VGPR headroom, no spill possible.
// 2-pass hi/lo (round-0 numerics); fully STATIC local indexing in the fold.
__global__ __launch_bounds__(512, 1) void gat2(
    const float* __restrict__ y1, const half_t* __restrict__ Wsw,
    const half_t* __restrict__ Zah, const half_t* __restrict__ Zal,
    float* __restrict__ out) {
    __shared__ __align__(16) half_t xsh[16 * 512];   // 16 KiB
    __shared__ __align__(16) half_t xsl[16 * 512];   // 16 KiB
    __shared__ float zpart[4][32][9];
    __shared__ __align__(16) float ge_s[4][32];
    __shared__ __align__(16) float att_s[4][32];
    __shared__ float outp_s[4][2][256];              // 8 KiB

    const int t = threadIdx.x;
    const int w = t >> 6, l = t & 63, lm = t & 31, q = (t >> 5) & 1;

    const float4* xg = (const float4*)(y1 + (size_t)blockIdx.x * 32 * 256);
    stage_chunk(xg, xsh, xsl, t);          // rows 0..15
    stage_chunk(xg, xsh, xsl, t + 512);    // rows 16..31
    __syncthreads();

    if (w < 4) z_phase(xsh, xsl, Zah, Zal, &zpart[w][0][0], w, l, lm, q);
    __syncthreads();

    if (t < 128) {
        int h = t >> 5, r = t & 31;
        int c0 = 2 * h, c1 = 2 * h + 1, rr = r & ~15;
        float own  = zpart[0][r][c0] + zpart[1][r][c0] + zpart[2][r][c0] + zpart[3][r][c0];
        float root = zpart[0][rr][c1] + zpart[1][rr][c1] + zpart[2][rr][c1] + zpart[3][rr][c1];
        ge_s[h][r] = gelu_exact(gelu_exact(own + root));
    }
    __syncthreads();
    if (t < 128) {
        int h = t >> 5, r = t & 31;
        int g0 = r & ~15;
        float mx = -1e30f;
#pragma unroll
        for (int i = 0; i < 16; ++i) mx = fmaxf(mx, ge_s[h][g0 + i]);
        float sum = 0.f;
#pragma unroll
        for (int i = 0; i < 16; ++i) sum += expf(ge_s[h][g0 + i] - mx);
        att_s[h][r] = expf(ge_s[h][r] - mx) / sum;
    }
    __syncthreads();

    // wave w: head h = w>>1, strip s = w&1 -> j-cols {4s..4s+3} (cols 128s..128s+127)
    const int h = w >> 1, s = w & 1;
    const half_t* Bp = Wsw + ((size_t)(h * 16) * 8 + 4 * s) * 512 + (size_t)l * 8;

    float tp[4][2];
#pragma unroll
    for (int jc = 0; jc < 4; ++jc) { tp[jc][0] = 0.f; tp[jc][1] = 0.f; }

#pragma unroll 1
    for (int pass = 0; pass < 2; ++pass) {
        const half_t* Xp = pass ? xsl : xsh;
        floatx16 acc[4];
#pragma unroll
        for (int jc = 0; jc < 4; ++jc) acc[jc] = zero16();
#pragma unroll
        for (int ks = 0; ks < 16; ++ks) {
            int ao = (ks * 64 + l) * 16;
            half8 a = lds_frag<true>(Xp, ao);
#pragma unroll
            for (int jc = 0; jc < 4; ++jc) {
                half8 b = *(const half8*)(Bp + (size_t)ks * 4096 + jc * 512);
                acc[jc] = MFMA16(a, b, acc[jc]);
            }
        }
        // STATIC fold: acc reg r = jj + 4*k2 + 8*g  <->  row = 16g + 8k2 + 4q + jj
#pragma unroll
        for (int g = 0; g < 2; ++g)
#pragma unroll
            for (int k2 = 0; k2 < 2; ++k2)
#pragma unroll
                for (int jj = 0; jj < 4; ++jj) {
                    float av = att_s[h][16 * g + 8 * k2 + 4 * q + jj];
                    int r = jj + 4 * k2 + 8 * g;
#pragma unroll
                    for (int jc = 0; jc < 4; ++jc)
                        tp[jc][g] = fmaf(acc[jc][r], av, tp[jc][g]);
                }
    }

#pragma unroll
    for (int g = 0; g < 2; ++g)
#pragma unroll
        for (int jc = 0; jc < 4; ++jc) {
            float sf = tp[jc][g] + __shfl_xor(tp[jc][g], 32, 64);
            if (q == 0) outp_s[h][g][128 * s + 32 * jc + lm] = gelu_exact(sf);
        }
    __syncthreads();

    {
        int g = t >> 8, col = t & 255;
        float sm = outp_s[0][g][col] + outp_s[1][g][col] + outp_s[2][g][col] + outp_s[3][g][col];
        out[((size_t)blockIdx.x * 2 + g) * 256 + col] = 0.25f * sm;
    }
}

extern "C" void kernel_launch(void* const* d_in, const int* in_sizes, int n_in,
                              void* d_out, int out_size, void* d_ws, size_t ws_size,
                              hipStream_t stream) {
    const float* x  = (const float*)d_in[0];
    const float* W0 = (const float*)d_in[1];
    const float* A0 = (const float*)d_in[2];
    const float* W1 = (const float*)d_in[3];
    const float* A1 = (const float*)d_in[4];

    char* ws = (char*)d_ws;
    float*  y1   = (float*)ws;                  // 8 MiB: [8192][256]
    half_t* Wsw0 = (half_t*)(ws + 8388608);     // 512 KiB
    half_t* Wsw1 = (half_t*)(ws + 8912896);     // 512 KiB
    half_t* Zah0 = (half_t*)(ws + 9437184);     // 16 KiB each
    half_t* Zal0 = (half_t*)(ws + 9453568);
    half_t* Zah1 = (half_t*)(ws + 9469952);
    half_t* Zal1 = (half_t*)(ws + 9486336);

    prep<<<64, 256, 0, stream>>>(W0, A0, W1, A1, Wsw0, Wsw1, Zah0, Zal0, Zah1, Zal1);
    gat_layer<4><<<2048, 256, 0, stream>>>(x, Wsw0, Zah0, Zal0, y1);
    gat2<<<256, 512, 0, stream>>>(y1, Wsw1, Zah1, Zal1, (float*)d_out);
}